// Round 1
// baseline (258.982 us; speedup 1.0000x reference)
//
#include <hip/hip_runtime.h>
#include <math.h>

#define BB 16
#define NN 256
#define LL 1024
#define DD 256

constexpr float LN_EPS = 1e-5f;
constexpr float NEG_SLOPE = 0.01f;

// ---------------------------------------------------------------------------
// prep: v1[d] = sum_e w1[e]*W_mol[e,d]; v2[d] = sum_e w2[e]*W_nb[e,d]
//       c[0] = b_mol·w1 + align_b ; c[1] = b_nb·w2
// ---------------------------------------------------------------------------
__global__ __launch_bounds__(256) void prep_kernel(
    const float* __restrict__ W_mol, const float* __restrict__ b_mol,
    const float* __restrict__ W_nb, const float* __restrict__ b_nb,
    const float* __restrict__ align_w, const float* __restrict__ align_b,
    float* __restrict__ v1, float* __restrict__ v2, float* __restrict__ c) {
  int d = threadIdx.x;
  float acc1 = 0.f, acc2 = 0.f;
  #pragma unroll 4
  for (int e = 0; e < DD; ++e) {
    acc1 += align_w[e] * W_mol[e * DD + d];
    acc2 += align_w[DD + e] * W_nb[e * DD + d];
  }
  v1[d] = acc1;
  v2[d] = acc2;

  __shared__ float red[256];
  red[d] = b_mol[d] * align_w[d];
  __syncthreads();
  for (int s = 128; s > 0; s >>= 1) {
    if (d < s) red[d] += red[d + s];
    __syncthreads();
  }
  if (d == 0) c[0] = red[0] + align_b[0];
  __syncthreads();
  red[d] = b_nb[d] * align_w[DD + d];
  __syncthreads();
  for (int s = 128; s > 0; s >>= 1) {
    if (d < s) red[d] += red[d + s];
    __syncthreads();
  }
  if (d == 0) c[1] = red[0];
}

// ---------------------------------------------------------------------------
// rowdot: out[row] = X[row,:]·v + *cadd   (one wave per row, 4 rows/block)
// ---------------------------------------------------------------------------
__global__ __launch_bounds__(256) void rowdot_kernel(
    const float* __restrict__ X, const float* __restrict__ v,
    const float* __restrict__ cadd, float* __restrict__ out) {
  int row = blockIdx.x * 4 + (threadIdx.x >> 6);
  int lane = threadIdx.x & 63;
  const float* xr = X + (size_t)row * DD;
  float s = 0.f;
  #pragma unroll
  for (int k = 0; k < 4; ++k) s += xr[lane + 64 * k] * v[lane + 64 * k];
  #pragma unroll
  for (int off = 32; off > 0; off >>= 1) s += __shfl_xor(s, off, 64);
  if (lane == 0) out[row] = s + cadd[0];
}

// ---------------------------------------------------------------------------
// agemm: a[row, e] = sum_d atom[row, d] * W_nb[e, d] + b_nb[e]
//   16 rows per block, 256 threads (thread = output column e).
//   W chunk staged transposed in LDS with +1 pad (row stride 257).
// ---------------------------------------------------------------------------
__global__ __launch_bounds__(256) void agemm_kernel(
    const float* __restrict__ atom, const float* __restrict__ W_nb,
    const float* __restrict__ b_nb, float* __restrict__ a_out) {
  __shared__ float atile[16][256];   // 16 KB
  __shared__ float wlds[32][257];    // ~32.9 KB, padded
  int t = threadIdx.x;
  int row0 = blockIdx.x * 16;

  #pragma unroll
  for (int k = 0; k < 16; ++k) {
    int lin = t + 256 * k;
    atile[lin >> 8][lin & 255] = atom[(size_t)row0 * DD + lin];
  }

  float bias = b_nb[t];
  float acc[16];
  #pragma unroll
  for (int r = 0; r < 16; ++r) acc[r] = bias;

  for (int d0 = 0; d0 < DD; d0 += 32) {
    __syncthreads();
    #pragma unroll
    for (int k = 0; k < 32; ++k) {
      int lin = t + 256 * k;
      int dc = lin & 31;
      int e2 = lin >> 5;
      wlds[dc][e2] = W_nb[e2 * DD + d0 + dc];
    }
    __syncthreads();
    #pragma unroll
    for (int dc = 0; dc < 32; ++dc) {
      float wv = wlds[dc][t];
      #pragma unroll
      for (int r = 0; r < 16; ++r) acc[r] += atile[r][d0 + dc] * wv;
    }
  }
  #pragma unroll
  for (int r = 0; r < 16; ++r) a_out[(size_t)(row0 + r) * DD + t] = acc[r];
}

// ---------------------------------------------------------------------------
// attn: per block: one b, 16 n-rows. 512 threads = 8 waves.
//  phase A: wave w owns rows 2w, 2w+1 — score+softmax fully in registers
//  phase B: thread (d = t&255, rh = t>>8) accumulates ctx for 8 rows
//  phase C: LN (wave shuffle stats) + store
// ---------------------------------------------------------------------------
__global__ __launch_bounds__(512) void attn_kernel(
    const float* __restrict__ a, const float* __restrict__ s1,
    const float* __restrict__ s2, const float* __restrict__ amask,
    const float* __restrict__ smask, const float* __restrict__ gamma,
    const float* __restrict__ beta, float* __restrict__ out) {
  __shared__ __align__(16) float attn[16][1024];   // 64 KB; reused as ctx[16][256]
  __shared__ float mu_s[16], rs_s[16];
  int b = blockIdx.x >> 4;
  int n0 = (blockIdx.x & 15) * 16;
  int t = threadIdx.x;
  int wave = t >> 6;
  int lane = t & 63;

  // ---- phase A: score + softmax (wave per 2 rows) ----
  {
    float s2v[16], amv[16], smv[16];
    #pragma unroll
    for (int k = 0; k < 16; ++k) {
      int l = lane + 64 * k;
      s2v[k] = s2[b * LL + l];
      amv[k] = amask[b * LL + l];
      smv[k] = smask[b * LL + l];
    }
    for (int rr = 0; rr < 2; ++rr) {
      int r = wave * 2 + rr;
      float s1v = s1[b * NN + n0 + r];
      float p[16];
      float mx = -INFINITY;
      #pragma unroll
      for (int k = 0; k < 16; ++k) {
        float sc = s1v + s2v[k];
        sc = sc > 0.f ? sc : NEG_SLOPE * sc;
        sc += smv[k];
        p[k] = sc;
        mx = fmaxf(mx, sc);
      }
      #pragma unroll
      for (int off = 32; off > 0; off >>= 1) mx = fmaxf(mx, __shfl_xor(mx, off, 64));
      float sum = 0.f;
      #pragma unroll
      for (int k = 0; k < 16; ++k) {
        p[k] = __expf(p[k] - mx);
        sum += p[k];
      }
      #pragma unroll
      for (int off = 32; off > 0; off >>= 1) sum += __shfl_xor(sum, off, 64);
      float inv = 1.f / sum;
      #pragma unroll
      for (int k = 0; k < 16; ++k) attn[r][lane + 64 * k] = p[k] * amv[k] * inv;
    }
  }
  __syncthreads();

  // ---- phase B: ctx[r][d] = sum_l attn[r][l] * a[b][l][d] ----
  int d = t & 255;
  int rh = t >> 8;   // 0/1 -> rows rh*8 .. rh*8+7
  float acc[8];
  #pragma unroll
  for (int r = 0; r < 8; ++r) acc[r] = 0.f;
  const float* ab = a + (size_t)b * LL * DD + d;
  for (int lc = 0; lc < LL / 4; ++lc) {
    float4 at[8];
    #pragma unroll
    for (int r = 0; r < 8; ++r)
      at[r] = *(const float4*)&attn[rh * 8 + r][lc * 4];
    float av0 = ab[(size_t)(4 * lc + 0) * DD];
    float av1 = ab[(size_t)(4 * lc + 1) * DD];
    float av2 = ab[(size_t)(4 * lc + 2) * DD];
    float av3 = ab[(size_t)(4 * lc + 3) * DD];
    #pragma unroll
    for (int r = 0; r < 8; ++r) {
      acc[r] += at[r].x * av0;
      acc[r] += at[r].y * av1;
      acc[r] += at[r].z * av2;
      acc[r] += at[r].w * av3;
    }
  }
  __syncthreads();

  // ---- phase C: LN ----
  float* ctx = &attn[0][0];   // reuse as [16][256]
  #pragma unroll
  for (int r = 0; r < 8; ++r) ctx[(rh * 8 + r) * 256 + d] = acc[r];
  __syncthreads();
  for (int rr = 0; rr < 2; ++rr) {
    int r = wave * 2 + rr;
    float s = 0.f, sq = 0.f;
    #pragma unroll
    for (int j = 0; j < 4; ++j) {
      float v = ctx[r * 256 + lane + 64 * j];
      s += v;
      sq += v * v;
    }
    #pragma unroll
    for (int off = 32; off > 0; off >>= 1) {
      s += __shfl_xor(s, off, 64);
      sq += __shfl_xor(sq, off, 64);
    }
    if (lane == 0) {
      float mu = s * (1.f / 256.f);
      float var = sq * (1.f / 256.f) - mu * mu;
      mu_s[r] = mu;
      rs_s[r] = rsqrtf(var + LN_EPS);
    }
  }
  __syncthreads();
  #pragma unroll
  for (int r = 0; r < 8; ++r) {
    int rr = rh * 8 + r;
    float v = ctx[rr * 256 + d];
    out[(size_t)(b * NN + n0 + rr) * DD + d] =
        (v - mu_s[rr]) * rs_s[rr] * gamma[d] + beta[d];
  }
}

// ---------------------------------------------------------------------------
extern "C" void kernel_launch(void* const* d_in, const int* in_sizes, int n_in,
                              void* d_out, int out_size, void* d_ws, size_t ws_size,
                              hipStream_t stream) {
  const float* mol     = (const float*)d_in[0];
  const float* atom    = (const float*)d_in[1];
  const float* amask   = (const float*)d_in[2];
  const float* smask   = (const float*)d_in[3];
  const float* W_mol   = (const float*)d_in[4];
  const float* b_mol   = (const float*)d_in[5];
  const float* W_nb    = (const float*)d_in[6];
  const float* b_nb    = (const float*)d_in[7];
  const float* align_w = (const float*)d_in[8];
  const float* align_b = (const float*)d_in[9];
  const float* gamma   = (const float*)d_in[10];
  const float* beta    = (const float*)d_in[11];
  float* outp = (float*)d_out;

  float* ws = (float*)d_ws;
  float* a  = ws;                       // B*L*D = 4194304 floats
  float* v1 = a + (size_t)BB * LL * DD; // 256
  float* v2 = v1 + 256;                 // 256
  float* c  = v2 + 256;                 // 2
  float* s1 = c + 2;                    // B*N = 4096
  float* s2 = s1 + BB * NN;             // B*L = 16384

  prep_kernel<<<1, 256, 0, stream>>>(W_mol, b_mol, W_nb, b_nb, align_w,
                                     align_b, v1, v2, c);
  rowdot_kernel<<<BB * NN / 4, 256, 0, stream>>>(mol, v1, c + 0, s1);
  rowdot_kernel<<<BB * LL / 4, 256, 0, stream>>>(atom, v2, c + 1, s2);
  agemm_kernel<<<BB * LL / 16, 256, 0, stream>>>(atom, W_nb, b_nb, a);
  attn_kernel<<<BB * (NN / 16), 512, 0, stream>>>(a, s1, s2, amask, smask,
                                                  gamma, beta, outp);
}

// Round 2
// 75.264 us; speedup vs baseline: 3.4410x; 3.4410x over previous
//
#include <hip/hip_runtime.h>
#include <math.h>

#define BB 16
#define NN 256
#define LL 1024
#define DD 256

constexpr float LN_EPS = 1e-5f;
constexpr float NEG_SLOPE = 0.01f;

typedef __attribute__((ext_vector_type(8))) short short8;
typedef __attribute__((ext_vector_type(4))) float f32x4;

static __device__ __forceinline__ unsigned short f2bf(float f) {
  union { float f; unsigned u; } v; v.f = f;
  unsigned r = v.u + 0x7FFFu + ((v.u >> 16) & 1u);
  return (unsigned short)(r >> 16);
}

// ---------------------------------------------------------------------------
// prep: blk0: v1[d]=sum_e w1[e]*W_mol[e,d], c0 = b_mol.w1 + align_b
//       blk1: v2[d]=sum_e w2[e]*W_nb[e,d],  c1 = b_nb.w2
//       blk2/3: convert W_nb -> bf16 Wb
// ---------------------------------------------------------------------------
__global__ __launch_bounds__(256) void prep_kernel(
    const float* __restrict__ W_mol, const float* __restrict__ b_mol,
    const float* __restrict__ W_nb, const float* __restrict__ b_nb,
    const float* __restrict__ align_w, const float* __restrict__ align_b,
    float* __restrict__ v1, float* __restrict__ v2, float* __restrict__ c,
    unsigned short* __restrict__ Wb) {
  int t = threadIdx.x;
  int blk = blockIdx.x;
  if (blk < 2) {
    const float* W = blk ? W_nb : W_mol;
    const float* wv = align_w + blk * DD;
    float acc = 0.f;
    #pragma unroll 4
    for (int e = 0; e < DD; ++e) acc += wv[e] * W[e * DD + t];
    (blk ? v2 : v1)[t] = acc;
    __shared__ float red[256];
    const float* bias = blk ? b_nb : b_mol;
    red[t] = bias[t] * wv[t];
    __syncthreads();
    for (int s = 128; s > 0; s >>= 1) {
      if (t < s) red[t] += red[t + s];
      __syncthreads();
    }
    if (t == 0) c[blk] = red[0] + (blk ? 0.f : align_b[0]);
  } else {
    int base = (blk - 2) * 32768;
    for (int i = t; i < 8192; i += 256) {
      float4 f = *(const float4*)&W_nb[base + i * 4];
      ushort4 o;
      o.x = f2bf(f.x); o.y = f2bf(f.y); o.z = f2bf(f.z); o.w = f2bf(f.w);
      *(ushort4*)&Wb[base + i * 4] = o;
    }
  }
}

// ---------------------------------------------------------------------------
// rowdot: out[row] = X[row,:]·v + *cadd   (one wave per row, 4 rows/block)
// ---------------------------------------------------------------------------
__global__ __launch_bounds__(256) void rowdot_kernel(
    const float* __restrict__ X, const float* __restrict__ v,
    const float* __restrict__ cadd, float* __restrict__ out) {
  int row = blockIdx.x * 4 + (threadIdx.x >> 6);
  int lane = threadIdx.x & 63;
  const float* xr = X + (size_t)row * DD;
  float s = 0.f;
  #pragma unroll
  for (int k = 0; k < 4; ++k) s += xr[lane + 64 * k] * v[lane + 64 * k];
  #pragma unroll
  for (int off = 32; off > 0; off >>= 1) s += __shfl_xor(s, off, 64);
  if (lane == 0) out[row] = s + cadd[0];
}

// ---------------------------------------------------------------------------
// agemm (MFMA): aT[b][e][l] = sum_d W_nb[e,d]*atom[b,l,d] + b_nb[e]  (bf16 out)
// Block: 256 thr = 4 waves. Block tile: all 256 e x 32 l. Wave: 64 e x 32 l.
// A-frag = Wb row (contig k), B-frag = atom row (f32->bf16 in-kernel).
// ---------------------------------------------------------------------------
__global__ __launch_bounds__(256) void agemm_kernel(
    const float* __restrict__ atom, const unsigned short* __restrict__ Wb,
    const float* __restrict__ b_nb, unsigned short* __restrict__ aT) {
  int t = threadIdx.x;
  int w = t >> 6, lane = t & 63;
  int b = blockIdx.x >> 5;
  int l0 = (blockIdx.x & 31) * 32;
  int lo16 = lane & 15, g = lane >> 4;
  int e_base = w * 64;

  f32x4 acc[4][2];
  #pragma unroll
  for (int m = 0; m < 4; ++m)
    #pragma unroll
    for (int n = 0; n < 2; ++n) acc[m][n] = f32x4{0.f, 0.f, 0.f, 0.f};

  const unsigned short* Ap = Wb + (size_t)(e_base + lo16) * DD + g * 8;
  const float* Bp = atom + (size_t)(b * LL + l0 + lo16) * DD + g * 8;

  #pragma unroll 2
  for (int kk = 0; kk < 8; ++kk) {
    short8 af[4];
    short8 bf[2];
    #pragma unroll
    for (int m = 0; m < 4; ++m)
      af[m] = *(const short8*)(Ap + m * 16 * DD + kk * 32);
    #pragma unroll
    for (int n = 0; n < 2; ++n) {
      float4 f0 = *(const float4*)(Bp + n * 16 * DD + kk * 32);
      float4 f1 = *(const float4*)(Bp + n * 16 * DD + kk * 32 + 4);
      short8 bv;
      bv[0] = (short)f2bf(f0.x); bv[1] = (short)f2bf(f0.y);
      bv[2] = (short)f2bf(f0.z); bv[3] = (short)f2bf(f0.w);
      bv[4] = (short)f2bf(f1.x); bv[5] = (short)f2bf(f1.y);
      bv[6] = (short)f2bf(f1.z); bv[7] = (short)f2bf(f1.w);
      bf[n] = bv;
    }
    #pragma unroll
    for (int m = 0; m < 4; ++m)
      #pragma unroll
      for (int n = 0; n < 2; ++n)
        acc[m][n] = __builtin_amdgcn_mfma_f32_16x16x32_bf16(af[m], bf[n],
                                                            acc[m][n], 0, 0, 0);
  }

  // epilogue: + bias, ->bf16, stage in LDS, coalesced store to aT
  __shared__ unsigned short sAT[256 * 36];  // row stride 36 (72B, 8B-aligned)
  #pragma unroll
  for (int m = 0; m < 4; ++m) {
    int e_lo = e_base + m * 16 + g * 4;
    float4 bias = *(const float4*)&b_nb[e_lo];
    #pragma unroll
    for (int n = 0; n < 2; ++n) {
      int l = n * 16 + lo16;
      #pragma unroll
      for (int j = 0; j < 4; ++j) {
        float v = acc[m][n][j] + ((const float*)&bias)[j];
        sAT[(e_lo + j) * 36 + l] = f2bf(v);
      }
    }
  }
  __syncthreads();
  unsigned short* dst = aT + (size_t)b * DD * LL + l0;
  #pragma unroll
  for (int idx = t; idx < 2048; idx += 256) {
    int e = idx >> 3, ch = idx & 7;
    ushort4 v = *(const ushort4*)&sAT[e * 36 + ch * 4];
    *(ushort4*)(dst + (size_t)e * LL + ch * 4) = v;
  }
}

// ---------------------------------------------------------------------------
// attn: block = (b, 16 n-rows), 256 thr = 4 waves.
//  A: softmax in registers (wave: 4 rows), store bf16 attn to LDS (XOR swizzle)
//  B: MFMA ctx = attn @ a using aT as B-operand; wave: d in [w*64, w*64+64)
//  C: LN + store
// ---------------------------------------------------------------------------
__global__ __launch_bounds__(256) void attn_kernel(
    const unsigned short* __restrict__ aT, const float* __restrict__ s1,
    const float* __restrict__ s2, const float* __restrict__ amask,
    const float* __restrict__ smask, const float* __restrict__ gamma,
    const float* __restrict__ beta, float* __restrict__ out) {
  __shared__ unsigned short sattn[16 * 1024];  // bf16, XOR-swizzled
  __shared__ float ctx[16][DD];
  __shared__ float mu_s[16], rs_s[16];
  int b = blockIdx.x >> 4;
  int n0 = (blockIdx.x & 15) * 16;
  int t = threadIdx.x, w = t >> 6, lane = t & 63;

  // ---- phase A ----
  {
    float s2v[16], amv[16], smv[16];
    #pragma unroll
    for (int k = 0; k < 16; ++k) {
      int l = lane + 64 * k;
      s2v[k] = s2[b * LL + l];
      amv[k] = amask[b * LL + l];
      smv[k] = smask[b * LL + l];
    }
    for (int rr = 0; rr < 4; ++rr) {
      int r = w * 4 + rr;
      float s1v = s1[b * NN + n0 + r];
      float p[16];
      float mx = -INFINITY;
      #pragma unroll
      for (int k = 0; k < 16; ++k) {
        float sc = s1v + s2v[k];
        sc = sc > 0.f ? sc : NEG_SLOPE * sc;
        sc += smv[k];
        p[k] = sc;
        mx = fmaxf(mx, sc);
      }
      #pragma unroll
      for (int off = 32; off > 0; off >>= 1) mx = fmaxf(mx, __shfl_xor(mx, off, 64));
      float sum = 0.f;
      #pragma unroll
      for (int k = 0; k < 16; ++k) {
        p[k] = __expf(p[k] - mx);
        sum += p[k];
      }
      #pragma unroll
      for (int off = 32; off > 0; off >>= 1) sum += __shfl_xor(sum, off, 64);
      float inv = 1.f / sum;
      #pragma unroll
      for (int k = 0; k < 16; ++k) {
        unsigned short bv = f2bf(p[k] * amv[k] * inv);
        int l = lane + 64 * k;
        int byte = ((r * 1024 + l) * 2) ^ ((r & 7) << 4);
        *(unsigned short*)((char*)sattn + byte) = bv;
      }
    }
  }
  __syncthreads();

  // ---- phase B: MFMA ----
  int lo16 = lane & 15, g = lane >> 4;
  f32x4 acc[4];
  #pragma unroll
  for (int n = 0; n < 4; ++n) acc[n] = f32x4{0.f, 0.f, 0.f, 0.f};
  const unsigned short* Bp =
      aT + (size_t)b * DD * LL + (size_t)(w * 64 + lo16) * LL + g * 8;
  #pragma unroll 4
  for (int kk = 0; kk < 32; ++kk) {
    short8 afr = *(const short8*)((const char*)sattn +
        (((lo16 * 1024 + kk * 32 + g * 8) * 2) ^ ((lo16 & 7) << 4)));
    #pragma unroll
    for (int n = 0; n < 4; ++n) {
      short8 bfr = *(const short8*)(Bp + (size_t)n * 16 * LL + kk * 32);
      acc[n] = __builtin_amdgcn_mfma_f32_16x16x32_bf16(afr, bfr, acc[n], 0, 0, 0);
    }
  }

  // ---- phase C: frags -> LDS, LN, store ----
  #pragma unroll
  for (int n = 0; n < 4; ++n)
    #pragma unroll
    for (int j = 0; j < 4; ++j)
      ctx[g * 4 + j][w * 64 + n * 16 + lo16] = acc[n][j];
  __syncthreads();
  for (int rr = 0; rr < 4; ++rr) {
    int r = w * 4 + rr;
    float s = 0.f, sq = 0.f;
    #pragma unroll
    for (int jj = 0; jj < 4; ++jj) {
      float v = ctx[r][lane + 64 * jj];
      s += v;
      sq += v * v;
    }
    #pragma unroll
    for (int off = 32; off > 0; off >>= 1) {
      s += __shfl_xor(s, off, 64);
      sq += __shfl_xor(sq, off, 64);
    }
    if (lane == 0) {
      float mu = s * (1.f / 256.f);
      float var = sq * (1.f / 256.f) - mu * mu;
      mu_s[r] = mu;
      rs_s[r] = rsqrtf(var + LN_EPS);
    }
  }
  __syncthreads();
  #pragma unroll
  for (int r = 0; r < 16; ++r) {
    float v = ctx[r][t];
    out[(size_t)(b * NN + n0 + r) * DD + t] =
        (v - mu_s[r]) * rs_s[r] * gamma[t] + beta[t];
  }
}

// ---------------------------------------------------------------------------
extern "C" void kernel_launch(void* const* d_in, const int* in_sizes, int n_in,
                              void* d_out, int out_size, void* d_ws, size_t ws_size,
                              hipStream_t stream) {
  const float* mol     = (const float*)d_in[0];
  const float* atom    = (const float*)d_in[1];
  const float* amask   = (const float*)d_in[2];
  const float* smask   = (const float*)d_in[3];
  const float* W_mol   = (const float*)d_in[4];
  const float* b_mol   = (const float*)d_in[5];
  const float* W_nb    = (const float*)d_in[6];
  const float* b_nb    = (const float*)d_in[7];
  const float* align_w = (const float*)d_in[8];
  const float* align_b = (const float*)d_in[9];
  const float* gamma   = (const float*)d_in[10];
  const float* beta    = (const float*)d_in[11];
  float* outp = (float*)d_out;

  char* wsb = (char*)d_ws;
  unsigned short* aT = (unsigned short*)wsb;                    // 8 MB
  unsigned short* Wb = (unsigned short*)(wsb + 8388608);        // 128 KB
  float* v1 = (float*)(wsb + 8388608 + 131072);
  float* v2 = v1 + 256;
  float* c  = v2 + 256;
  float* s1 = c + 2;
  float* s2 = s1 + BB * NN;

  prep_kernel<<<4, 256, 0, stream>>>(W_mol, b_mol, W_nb, b_nb, align_w,
                                     align_b, v1, v2, c, Wb);
  rowdot_kernel<<<BB * NN / 4, 256, 0, stream>>>(mol, v1, c + 0, s1);
  rowdot_kernel<<<BB * LL / 4, 256, 0, stream>>>(atom, v2, c + 1, s2);
  agemm_kernel<<<BB * (LL / 32), 256, 0, stream>>>(atom, Wb, b_nb, aT);
  attn_kernel<<<BB * (NN / 16), 256, 0, stream>>>(aT, s1, s2, amask, smask,
                                                  gamma, beta, outp);
}

// Round 3
// 66.982 us; speedup vs baseline: 3.8665x; 1.1236x over previous
//
#include <hip/hip_runtime.h>
#include <math.h>

#define BB 16
#define NN 256
#define LL 1024
#define DD 256

constexpr float LN_EPS = 1e-5f;
constexpr float NEG_SLOPE = 0.01f;

typedef __attribute__((ext_vector_type(8))) short short8;
typedef __attribute__((ext_vector_type(4))) float f32x4;

static __device__ __forceinline__ unsigned short f2bf(float f) {
  union { float f; unsigned u; } v; v.f = f;
  unsigned r = v.u + 0x7FFFu + ((v.u >> 16) & 1u);
  return (unsigned short)(r >> 16);
}

// ---------------------------------------------------------------------------
// prep: blk0: v1[d]=sum_e w1[e]*W_mol[e,d], c0 = b_mol.w1 + align_b
//       blk1: v2[d]=sum_e w2[e]*W_nb[e,d],  c1 = b_nb.w2
// 1024 threads: thread (d = t&255, eq = t>>8) sums 64 e's, LDS-reduce.
// ---------------------------------------------------------------------------
__global__ __launch_bounds__(1024) void prep_kernel(
    const float* __restrict__ W_mol, const float* __restrict__ b_mol,
    const float* __restrict__ W_nb, const float* __restrict__ b_nb,
    const float* __restrict__ align_w, const float* __restrict__ align_b,
    float* __restrict__ v1, float* __restrict__ v2, float* __restrict__ c) {
  int blk = blockIdx.x;
  const float* W = blk ? W_nb : W_mol;
  const float* wv = align_w + blk * DD;
  const float* bias = blk ? b_nb : b_mol;
  int t = threadIdx.x;
  int d = t & 255, eq = t >> 8;
  float acc = 0.f;
  #pragma unroll 8
  for (int e = eq * 64; e < eq * 64 + 64; ++e) acc += wv[e] * W[e * DD + d];
  __shared__ float part[4][256];
  part[eq][d] = acc;
  __syncthreads();
  if (eq == 0)
    (blk ? v2 : v1)[d] = part[0][d] + part[1][d] + part[2][d] + part[3][d];

  __shared__ float red[256];
  if (eq == 0) red[d] = bias[d] * wv[d];
  __syncthreads();
  for (int s = 128; s > 0; s >>= 1) {
    if (t < s) red[t] += red[t + s];
    __syncthreads();
  }
  if (t == 0) c[blk] = red[0] + (blk ? 0.f : align_b[0]);
}

// ---------------------------------------------------------------------------
// agemm (MFMA): aT[b][e][l] = sum_d W_nb[e,d]*atom[b,l,d] + b_nb[e]  (bf16)
// Also: s2[b][l] = atom[b,l,:]·v2 + c1  for this block's 32 l-rows.
// Block: 256 thr = 4 waves; tile 256e x 32l; wave 64e x 32l.
// W_nb converted f32->bf16 inline (L2-resident, no precompute pass).
// ---------------------------------------------------------------------------
__global__ __launch_bounds__(256) void agemm_kernel(
    const float* __restrict__ atom, const float* __restrict__ W_nb,
    const float* __restrict__ b_nb, const float* __restrict__ v2,
    const float* __restrict__ c, unsigned short* __restrict__ aT,
    float* __restrict__ s2) {
  int t = threadIdx.x;
  int w = t >> 6, lane = t & 63;
  int b = blockIdx.x >> 5;
  int l0 = (blockIdx.x & 31) * 32;
  int lo16 = lane & 15, g = lane >> 4;
  int e_base = w * 64;

  // ---- s2 for rows l0..l0+31 (8 threads per row, shuffle reduce) ----
  {
    int rr = t >> 3, dc = (t & 7) * 32;
    const float* ar = atom + (size_t)(b * LL + l0 + rr) * DD + dc;
    float s = 0.f;
    #pragma unroll
    for (int i = 0; i < 8; ++i) {
      float4 f = *(const float4*)(ar + i * 4);
      s += f.x * v2[dc + i * 4] + f.y * v2[dc + i * 4 + 1] +
           f.z * v2[dc + i * 4 + 2] + f.w * v2[dc + i * 4 + 3];
    }
    s += __shfl_xor(s, 1, 64);
    s += __shfl_xor(s, 2, 64);
    s += __shfl_xor(s, 4, 64);
    if ((t & 7) == 0) s2[b * LL + l0 + rr] = s + c[1];
  }

  // ---- MFMA ----
  f32x4 acc[4][2];
  #pragma unroll
  for (int m = 0; m < 4; ++m)
    #pragma unroll
    for (int n = 0; n < 2; ++n) acc[m][n] = f32x4{0.f, 0.f, 0.f, 0.f};

  const float* Ap = W_nb + (size_t)(e_base + lo16) * DD + g * 8;
  const float* Bp = atom + (size_t)(b * LL + l0 + lo16) * DD + g * 8;

  #pragma unroll 2
  for (int kk = 0; kk < 8; ++kk) {
    short8 af[4];
    short8 bf[2];
    #pragma unroll
    for (int m = 0; m < 4; ++m) {
      float4 f0 = *(const float4*)(Ap + m * 16 * DD + kk * 32);
      float4 f1 = *(const float4*)(Ap + m * 16 * DD + kk * 32 + 4);
      short8 av;
      av[0] = (short)f2bf(f0.x); av[1] = (short)f2bf(f0.y);
      av[2] = (short)f2bf(f0.z); av[3] = (short)f2bf(f0.w);
      av[4] = (short)f2bf(f1.x); av[5] = (short)f2bf(f1.y);
      av[6] = (short)f2bf(f1.z); av[7] = (short)f2bf(f1.w);
      af[m] = av;
    }
    #pragma unroll
    for (int n = 0; n < 2; ++n) {
      float4 f0 = *(const float4*)(Bp + n * 16 * DD + kk * 32);
      float4 f1 = *(const float4*)(Bp + n * 16 * DD + kk * 32 + 4);
      short8 bv;
      bv[0] = (short)f2bf(f0.x); bv[1] = (short)f2bf(f0.y);
      bv[2] = (short)f2bf(f0.z); bv[3] = (short)f2bf(f0.w);
      bv[4] = (short)f2bf(f1.x); bv[5] = (short)f2bf(f1.y);
      bv[6] = (short)f2bf(f1.z); bv[7] = (short)f2bf(f1.w);
      bf[n] = bv;
    }
    #pragma unroll
    for (int m = 0; m < 4; ++m)
      #pragma unroll
      for (int n = 0; n < 2; ++n)
        acc[m][n] = __builtin_amdgcn_mfma_f32_16x16x32_bf16(af[m], bf[n],
                                                            acc[m][n], 0, 0, 0);
  }

  // epilogue: + bias, ->bf16, stage in LDS, coalesced store to aT
  __shared__ unsigned short sAT[256 * 36];  // row stride 36 (72B)
  #pragma unroll
  for (int m = 0; m < 4; ++m) {
    int e_lo = e_base + m * 16 + g * 4;
    float4 bias = *(const float4*)&b_nb[e_lo];
    #pragma unroll
    for (int n = 0; n < 2; ++n) {
      int l = n * 16 + lo16;
      #pragma unroll
      for (int j = 0; j < 4; ++j) {
        float v = acc[m][n][j] + ((const float*)&bias)[j];
        sAT[(e_lo + j) * 36 + l] = f2bf(v);
      }
    }
  }
  __syncthreads();
  unsigned short* dst = aT + (size_t)b * DD * LL + l0;
  #pragma unroll
  for (int idx = t; idx < 2048; idx += 256) {
    int e = idx >> 3, ch = idx & 7;
    ushort4 v = *(const ushort4*)&sAT[e * 36 + ch * 4];
    *(ushort4*)(dst + (size_t)e * LL + ch * 4) = v;
  }
}

// ---------------------------------------------------------------------------
// attn: block = (b, 16 n-rows), 256 thr = 4 waves.
//  s1 computed in-block (16 thr/row shuffle reduce from mol & v1)
//  A: softmax in registers (wave: 4 rows), bf16 attn -> LDS (XOR swizzle)
//  B: MFMA ctx = attn @ a using aT as B-operand; wave: d in [w*64, w*64+64)
//  C: LN + store
// ---------------------------------------------------------------------------
__global__ __launch_bounds__(256) void attn_kernel(
    const unsigned short* __restrict__ aT, const float* __restrict__ mol,
    const float* __restrict__ v1, const float* __restrict__ c,
    const float* __restrict__ s2, const float* __restrict__ amask,
    const float* __restrict__ smask, const float* __restrict__ gamma,
    const float* __restrict__ beta, float* __restrict__ out) {
  __shared__ unsigned short sattn[16 * 1024];  // bf16, XOR-swizzled
  __shared__ float ctx[16][DD];
  __shared__ float mu_s[16], rs_s[16];
  __shared__ float s1s[16];
  int b = blockIdx.x >> 4;
  int n0 = (blockIdx.x & 15) * 16;
  int t = threadIdx.x, w = t >> 6, lane = t & 63;

  // ---- s1 for rows n0..n0+15 ----
  {
    int r = t >> 4, dc = (t & 15) * 16;
    const float* mr = mol + (size_t)(b * NN + n0 + r) * DD + dc;
    float s = 0.f;
    #pragma unroll
    for (int i = 0; i < 4; ++i) {
      float4 f = *(const float4*)(mr + i * 4);
      s += f.x * v1[dc + i * 4] + f.y * v1[dc + i * 4 + 1] +
           f.z * v1[dc + i * 4 + 2] + f.w * v1[dc + i * 4 + 3];
    }
    s += __shfl_xor(s, 1, 64);
    s += __shfl_xor(s, 2, 64);
    s += __shfl_xor(s, 4, 64);
    s += __shfl_xor(s, 8, 64);
    if ((t & 15) == 0) s1s[r] = s + c[0];
  }
  __syncthreads();

  // ---- phase A: softmax ----
  {
    float s2v[16], amv[16], smv[16];
    #pragma unroll
    for (int k = 0; k < 16; ++k) {
      int l = lane + 64 * k;
      s2v[k] = s2[b * LL + l];
      amv[k] = amask[b * LL + l];
      smv[k] = smask[b * LL + l];
    }
    for (int rr = 0; rr < 4; ++rr) {
      int r = w * 4 + rr;
      float s1v = s1s[r];
      float p[16];
      float mx = -INFINITY;
      #pragma unroll
      for (int k = 0; k < 16; ++k) {
        float sc = s1v + s2v[k];
        sc = sc > 0.f ? sc : NEG_SLOPE * sc;
        sc += smv[k];
        p[k] = sc;
        mx = fmaxf(mx, sc);
      }
      #pragma unroll
      for (int off = 32; off > 0; off >>= 1) mx = fmaxf(mx, __shfl_xor(mx, off, 64));
      float sum = 0.f;
      #pragma unroll
      for (int k = 0; k < 16; ++k) {
        p[k] = __expf(p[k] - mx);
        sum += p[k];
      }
      #pragma unroll
      for (int off = 32; off > 0; off >>= 1) sum += __shfl_xor(sum, off, 64);
      float inv = 1.f / sum;
      #pragma unroll
      for (int k = 0; k < 16; ++k) {
        unsigned short bv = f2bf(p[k] * amv[k] * inv);
        int l = lane + 64 * k;
        int byte = ((r * 1024 + l) * 2) ^ ((r & 7) << 4);
        *(unsigned short*)((char*)sattn + byte) = bv;
      }
    }
  }
  __syncthreads();

  // ---- phase B: MFMA ----
  int lo16 = lane & 15, g = lane >> 4;
  f32x4 acc[4];
  #pragma unroll
  for (int n = 0; n < 4; ++n) acc[n] = f32x4{0.f, 0.f, 0.f, 0.f};
  const unsigned short* Bp =
      aT + (size_t)b * DD * LL + (size_t)(w * 64 + lo16) * LL + g * 8;
  #pragma unroll 4
  for (int kk = 0; kk < 32; ++kk) {
    short8 afr = *(const short8*)((const char*)sattn +
        (((lo16 * 1024 + kk * 32 + g * 8) * 2) ^ ((lo16 & 7) << 4)));
    #pragma unroll
    for (int n = 0; n < 4; ++n) {
      short8 bfr = *(const short8*)(Bp + (size_t)n * 16 * LL + kk * 32);
      acc[n] = __builtin_amdgcn_mfma_f32_16x16x32_bf16(afr, bfr, acc[n], 0, 0, 0);
    }
  }

  // ---- phase C: frags -> LDS, LN, store ----
  #pragma unroll
  for (int n = 0; n < 4; ++n)
    #pragma unroll
    for (int j = 0; j < 4; ++j)
      ctx[g * 4 + j][w * 64 + n * 16 + lo16] = acc[n][j];
  __syncthreads();
  for (int rr = 0; rr < 4; ++rr) {
    int r = w * 4 + rr;
    float s = 0.f, sq = 0.f;
    #pragma unroll
    for (int jj = 0; jj < 4; ++jj) {
      float v = ctx[r][lane + 64 * jj];
      s += v;
      sq += v * v;
    }
    #pragma unroll
    for (int off = 32; off > 0; off >>= 1) {
      s += __shfl_xor(s, off, 64);
      sq += __shfl_xor(sq, off, 64);
    }
    if (lane == 0) {
      float mu = s * (1.f / 256.f);
      float var = sq * (1.f / 256.f) - mu * mu;
      mu_s[r] = mu;
      rs_s[r] = rsqrtf(var + LN_EPS);
    }
  }
  __syncthreads();
  #pragma unroll
  for (int r = 0; r < 16; ++r) {
    float v = ctx[r][t];
    out[(size_t)(b * NN + n0 + r) * DD + t] =
        (v - mu_s[r]) * rs_s[r] * gamma[t] + beta[t];
  }
}

// ---------------------------------------------------------------------------
extern "C" void kernel_launch(void* const* d_in, const int* in_sizes, int n_in,
                              void* d_out, int out_size, void* d_ws, size_t ws_size,
                              hipStream_t stream) {
  const float* mol     = (const float*)d_in[0];
  const float* atom    = (const float*)d_in[1];
  const float* amask   = (const float*)d_in[2];
  const float* smask   = (const float*)d_in[3];
  const float* W_mol   = (const float*)d_in[4];
  const float* b_mol   = (const float*)d_in[5];
  const float* W_nb    = (const float*)d_in[6];
  const float* b_nb    = (const float*)d_in[7];
  const float* align_w = (const float*)d_in[8];
  const float* align_b = (const float*)d_in[9];
  const float* gamma   = (const float*)d_in[10];
  const float* beta    = (const float*)d_in[11];
  float* outp = (float*)d_out;

  char* wsb = (char*)d_ws;
  unsigned short* aT = (unsigned short*)wsb;          // 8 MB
  float* s2 = (float*)(wsb + 8388608);                // 64 KB
  float* v1 = s2 + BB * LL;
  float* v2 = v1 + 256;
  float* c  = v2 + 256;

  prep_kernel<<<2, 1024, 0, stream>>>(W_mol, b_mol, W_nb, b_nb, align_w,
                                      align_b, v1, v2, c);
  agemm_kernel<<<BB * (LL / 32), 256, 0, stream>>>(atom, W_nb, b_nb, v2, c,
                                                   aT, s2);
  attn_kernel<<<BB * (NN / 16), 256, 0, stream>>>(aT, mol, v1, c, s2, amask,
                                                  smask, gamma, beta, outp);
}

// Round 4
// 52.721 us; speedup vs baseline: 4.9123x; 1.2705x over previous
//
#include <hip/hip_runtime.h>
#include <math.h>

#define BB 16
#define NN 256
#define LL 1024
#define DD 256

constexpr float LN_EPS = 1e-5f;
constexpr float NEG_SLOPE = 0.01f;

typedef __attribute__((ext_vector_type(8))) short short8;
typedef __attribute__((ext_vector_type(4))) float f32x4;

static __device__ __forceinline__ unsigned short f2bf(float f) {
  union { float f; unsigned u; } v; v.f = f;
  unsigned r = v.u + 0x7FFFu + ((v.u >> 16) & 1u);
  return (unsigned short)(r >> 16);
}
static __device__ __forceinline__ float bf2f(unsigned short u) {
  union { unsigned u; float f; } v; v.u = ((unsigned)u) << 16;
  return v.f;
}

// ---------------------------------------------------------------------------
// agemm (MFMA): aT[b][e][l] = sum_d W_nb[e,d]*atom[b,l,d] + b_nb[e]  (bf16)
//   + s2[b][l] = sum_e w2[e]*a[e][l]   (from sAT; bias folds in c1)
//   + blocks 0..15 side-job: v1[d0..d0+15] = W_mol^T w1; block0: c0.
// 256 blocks x 512 thr (8 waves). Block tile 256e x 64l; wave 64e x 32l.
// XCD swizzle: all blocks of batch b land on XCD b&7.
// ---------------------------------------------------------------------------
__global__ __launch_bounds__(512) void agemm_kernel(
    const float* __restrict__ atom, const float* __restrict__ W_nb,
    const float* __restrict__ b_nb, const float* __restrict__ W_mol,
    const float* __restrict__ b_mol, const float* __restrict__ align_w,
    const float* __restrict__ align_b, unsigned short* __restrict__ aT,
    float* __restrict__ s2, float* __restrict__ v1c) {
  int t = threadIdx.x;
  int w = t >> 6, lane = t & 63;
  int i = blockIdx.x;
  int x = i & 7, k = i >> 3;
  int b = x + 8 * (k >> 4);          // all blocks of b on XCD b&7
  int l0 = (k & 15) * 64;
  int lo16 = lane & 15, g = lane >> 4;
  int e0 = (w & 3) * 64;
  int lsub = (w >> 2) * 32;

  // ---- side job: v1 columns (blocks 0..15), c0 (block 0) ----
  __shared__ float vp[32][16];
  if (i < 16) {
    int d0 = i * 16;
    int dl = t & 15, eseg = t >> 4;
    float acc = 0.f;
    #pragma unroll
    for (int q = 0; q < 8; ++q) {
      int e = eseg * 8 + q;
      acc += align_w[e] * W_mol[e * DD + d0 + dl];
    }
    vp[eseg][dl] = acc;
    __syncthreads();
    if (t < 16) {
      float s = 0.f;
      #pragma unroll
      for (int q = 0; q < 32; ++q) s += vp[q][t];
      v1c[d0 + t] = s;
    }
    if (i == 0 && w == 1) {
      float s = b_mol[lane] * align_w[lane] +
                b_mol[lane + 64] * align_w[lane + 64] +
                b_mol[lane + 128] * align_w[lane + 128] +
                b_mol[lane + 192] * align_w[lane + 192];
      #pragma unroll
      for (int off = 32; off > 0; off >>= 1) s += __shfl_xor(s, off, 64);
      if (lane == 0) v1c[256] = s + align_b[0];
    }
  }

  // ---- MFMA main ----
  f32x4 acc[4][2];
  #pragma unroll
  for (int m = 0; m < 4; ++m)
    #pragma unroll
    for (int n = 0; n < 2; ++n) acc[m][n] = f32x4{0.f, 0.f, 0.f, 0.f};

  const float* Ap = W_nb + (size_t)(e0 + lo16) * DD + g * 8;
  const float* Bp = atom + (size_t)(b * LL + l0 + lsub + lo16) * DD + g * 8;

  #pragma unroll 2
  for (int kk = 0; kk < 8; ++kk) {
    short8 af[4];
    short8 bf[2];
    #pragma unroll
    for (int m = 0; m < 4; ++m) {
      float4 f0 = *(const float4*)(Ap + m * 16 * DD + kk * 32);
      float4 f1 = *(const float4*)(Ap + m * 16 * DD + kk * 32 + 4);
      short8 av;
      av[0] = (short)f2bf(f0.x); av[1] = (short)f2bf(f0.y);
      av[2] = (short)f2bf(f0.z); av[3] = (short)f2bf(f0.w);
      av[4] = (short)f2bf(f1.x); av[5] = (short)f2bf(f1.y);
      av[6] = (short)f2bf(f1.z); av[7] = (short)f2bf(f1.w);
      af[m] = av;
    }
    #pragma unroll
    for (int n = 0; n < 2; ++n) {
      float4 f0 = *(const float4*)(Bp + n * 16 * DD + kk * 32);
      float4 f1 = *(const float4*)(Bp + n * 16 * DD + kk * 32 + 4);
      short8 bv;
      bv[0] = (short)f2bf(f0.x); bv[1] = (short)f2bf(f0.y);
      bv[2] = (short)f2bf(f0.z); bv[3] = (short)f2bf(f0.w);
      bv[4] = (short)f2bf(f1.x); bv[5] = (short)f2bf(f1.y);
      bv[6] = (short)f2bf(f1.z); bv[7] = (short)f2bf(f1.w);
      bf[n] = bv;
    }
    #pragma unroll
    for (int m = 0; m < 4; ++m)
      #pragma unroll
      for (int n = 0; n < 2; ++n)
        acc[m][n] = __builtin_amdgcn_mfma_f32_16x16x32_bf16(af[m], bf[n],
                                                            acc[m][n], 0, 0, 0);
  }

  // ---- epilogue: +bias, ->bf16 into LDS [256 e][68 l-stride] ----
  __shared__ unsigned short sAT[256 * 68];  // 34 KB
  #pragma unroll
  for (int m = 0; m < 4; ++m) {
    int e_lo = e0 + m * 16 + g * 4;
    float4 bias = *(const float4*)&b_nb[e_lo];
    #pragma unroll
    for (int n = 0; n < 2; ++n) {
      int l = lsub + n * 16 + lo16;
      #pragma unroll
      for (int j = 0; j < 4; ++j) {
        float v = acc[m][n][j] + ((const float*)&bias)[j];
        sAT[(e_lo + j) * 68 + l] = f2bf(v);
      }
    }
  }
  __syncthreads();

  // ---- s2 from sAT: l = t>>3 (64 rows), e-chunk = (t&7)*32 ----
  {
    int l = t >> 3, ech = (t & 7) * 32;
    float s = 0.f;
    #pragma unroll 8
    for (int q = 0; q < 32; ++q) {
      int e = ech + q;
      s += align_w[DD + e] * bf2f(sAT[e * 68 + l]);
    }
    s += __shfl_xor(s, 1, 64);
    s += __shfl_xor(s, 2, 64);
    s += __shfl_xor(s, 4, 64);
    if ((t & 7) == 0) s2[b * LL + l0 + l] = s;
  }

  // ---- coalesced store to aT ----
  unsigned short* dst = aT + (size_t)b * DD * LL + l0;
  #pragma unroll
  for (int idx = t; idx < 4096; idx += 512) {
    int e = idx >> 4, ch = idx & 15;
    ushort4 v = *(const ushort4*)&sAT[e * 68 + ch * 4];
    *(ushort4*)(dst + (size_t)e * LL + ch * 4) = v;
  }
}

// ---------------------------------------------------------------------------
// attn: block = (b, 16 n-rows), 512 thr = 8 waves. Same XCD swizzle (b&7).
//  s1 in-block from mol & v1 (ws); softmax (wave: 2 rows) -> bf16 LDS (XOR);
//  MFMA split-K: wave = e-quadrant x l-half, partial ctx; LN + store.
// ---------------------------------------------------------------------------
__global__ __launch_bounds__(512) void attn_kernel(
    const unsigned short* __restrict__ aT, const float* __restrict__ mol,
    const float* __restrict__ v1c, const float* __restrict__ s2,
    const float* __restrict__ amask, const float* __restrict__ smask,
    const float* __restrict__ gamma, const float* __restrict__ beta,
    float* __restrict__ out) {
  __shared__ unsigned short sattn[16 * 1024];  // 32 KB, XOR-swizzled
  __shared__ float ctxp[2][16][DD];            // 32 KB
  __shared__ float v1s[256];
  __shared__ float s1s[16];
  __shared__ float mu_s[16], rs_s[16];
  int i = blockIdx.x;
  int x = i & 7, k = i >> 3;
  int b = x + 8 * (k >> 4);
  int n0 = (k & 15) * 16;
  int t = threadIdx.x, w = t >> 6, lane = t & 63;

  float c0 = v1c[256];
  if (t < 256) v1s[t] = v1c[t];
  __syncthreads();

  // ---- s1: 32 thr/row ----
  {
    int r = t >> 5, off = (t & 31) * 8;
    const float* mr = mol + (size_t)(b * NN + n0 + r) * DD + off;
    float s = 0.f;
    #pragma unroll
    for (int q = 0; q < 2; ++q) {
      float4 f = *(const float4*)(mr + q * 4);
      s += f.x * v1s[off + q * 4] + f.y * v1s[off + q * 4 + 1] +
           f.z * v1s[off + q * 4 + 2] + f.w * v1s[off + q * 4 + 3];
    }
    s += __shfl_xor(s, 1, 64);
    s += __shfl_xor(s, 2, 64);
    s += __shfl_xor(s, 4, 64);
    s += __shfl_xor(s, 8, 64);
    s += __shfl_xor(s, 16, 64);
    if ((t & 31) == 0) s1s[r] = s + c0;
  }
  __syncthreads();

  // ---- softmax: wave w -> rows 2w, 2w+1 ----
  {
    float s2v[16], amv[16], smv[16];
    #pragma unroll
    for (int q = 0; q < 16; ++q) {
      int l = lane + 64 * q;
      s2v[q] = s2[b * LL + l];
      amv[q] = amask[b * LL + l];
      smv[q] = smask[b * LL + l];
    }
    #pragma unroll
    for (int rr = 0; rr < 2; ++rr) {
      int r = w * 2 + rr;
      float s1v = s1s[r];
      float p[16];
      float mx = -INFINITY;
      #pragma unroll
      for (int q = 0; q < 16; ++q) {
        float sc = s1v + s2v[q];
        sc = sc > 0.f ? sc : NEG_SLOPE * sc;
        sc += smv[q];
        p[q] = sc;
        mx = fmaxf(mx, sc);
      }
      #pragma unroll
      for (int off = 32; off > 0; off >>= 1) mx = fmaxf(mx, __shfl_xor(mx, off, 64));
      float sum = 0.f;
      #pragma unroll
      for (int q = 0; q < 16; ++q) {
        p[q] = __expf(p[q] - mx);
        sum += p[q];
      }
      #pragma unroll
      for (int off = 32; off > 0; off >>= 1) sum += __shfl_xor(sum, off, 64);
      float inv = 1.f / sum;
      #pragma unroll
      for (int q = 0; q < 16; ++q) {
        unsigned short bv = f2bf(p[q] * amv[q] * inv);
        int l = lane + 64 * q;
        int byte = ((r * 1024 + l) * 2) ^ ((r & 7) << 4);
        *(unsigned short*)((char*)sattn + byte) = bv;
      }
    }
  }
  __syncthreads();

  // ---- MFMA: wave = e-quadrant (w&3) x l-half (w>>2) ----
  int lo16 = lane & 15, g = lane >> 4;
  int e0 = (w & 3) * 64, lh = w >> 2;
  f32x4 acc[4];
  #pragma unroll
  for (int n = 0; n < 4; ++n) acc[n] = f32x4{0.f, 0.f, 0.f, 0.f};
  const unsigned short* Bp =
      aT + (size_t)b * DD * LL + (size_t)(e0 + lo16) * LL + lh * 512 + g * 8;
  #pragma unroll 4
  for (int kk = 0; kk < 16; ++kk) {
    short8 afr = *(const short8*)((const char*)sattn +
        (((lo16 * 1024 + lh * 512 + kk * 32 + g * 8) * 2) ^ ((lo16 & 7) << 4)));
    #pragma unroll
    for (int n = 0; n < 4; ++n) {
      short8 bfr = *(const short8*)(Bp + (size_t)n * 16 * LL + kk * 32);
      acc[n] = __builtin_amdgcn_mfma_f32_16x16x32_bf16(afr, bfr, acc[n], 0, 0, 0);
    }
  }
  #pragma unroll
  for (int n = 0; n < 4; ++n)
    #pragma unroll
    for (int j = 0; j < 4; ++j)
      ctxp[lh][g * 4 + j][e0 + n * 16 + lo16] = acc[n][j];
  __syncthreads();

  // ---- LN stats: wave w -> rows 2w, 2w+1 ----
  #pragma unroll
  for (int rr = 0; rr < 2; ++rr) {
    int r = w * 2 + rr;
    float s = 0.f, sq = 0.f;
    #pragma unroll
    for (int jj = 0; jj < 4; ++jj) {
      int cc = lane + 64 * jj;
      float v = ctxp[0][r][cc] + ctxp[1][r][cc];
      s += v;
      sq += v * v;
    }
    #pragma unroll
    for (int off = 32; off > 0; off >>= 1) {
      s += __shfl_xor(s, off, 64);
      sq += __shfl_xor(sq, off, 64);
    }
    if (lane == 0) {
      float mu = s * (1.f / 256.f);
      float var = sq * (1.f / 256.f) - mu * mu;
      mu_s[r] = mu;
      rs_s[r] = rsqrtf(var + LN_EPS);
    }
  }
  __syncthreads();

  // ---- store ----
  #pragma unroll
  for (int q = 0; q < 8; ++q) {
    int idx = t + 512 * q;
    int r = idx >> 8, d = idx & 255;
    float v = ctxp[0][r][d] + ctxp[1][r][d];
    out[(size_t)(b * NN + n0 + r) * DD + d] =
        (v - mu_s[r]) * rs_s[r] * gamma[d] + beta[d];
  }
}

// ---------------------------------------------------------------------------
extern "C" void kernel_launch(void* const* d_in, const int* in_sizes, int n_in,
                              void* d_out, int out_size, void* d_ws, size_t ws_size,
                              hipStream_t stream) {
  const float* mol     = (const float*)d_in[0];
  const float* atom    = (const float*)d_in[1];
  const float* amask   = (const float*)d_in[2];
  const float* smask   = (const float*)d_in[3];
  const float* W_mol   = (const float*)d_in[4];
  const float* b_mol   = (const float*)d_in[5];
  const float* W_nb    = (const float*)d_in[6];
  const float* b_nb    = (const float*)d_in[7];
  const float* align_w = (const float*)d_in[8];
  const float* align_b = (const float*)d_in[9];
  const float* gamma   = (const float*)d_in[10];
  const float* beta    = (const float*)d_in[11];
  float* outp = (float*)d_out;

  char* wsb = (char*)d_ws;
  unsigned short* aT = (unsigned short*)wsb;          // 8 MB
  float* s2  = (float*)(wsb + 8388608);               // 64 KB
  float* v1c = s2 + BB * LL;                          // 257 floats

  agemm_kernel<<<256, 512, 0, stream>>>(atom, W_nb, b_nb, W_mol, b_mol,
                                        align_w, align_b, aT, s2, v1c);
  attn_kernel<<<256, 512, 0, stream>>>(aT, mol, v1c, s2, amask, smask,
                                       gamma, beta, outp);
}

// Round 5
// 40.788 us; speedup vs baseline: 6.3494x; 1.2926x over previous
//
#include <hip/hip_runtime.h>
#include <hip/hip_bf16.h>
#include <math.h>

#define BB 16
#define NN 256
#define LL 1024
#define DD 256

constexpr float LN_EPS = 1e-5f;
constexpr float NEG_SLOPE = 0.01f;

typedef __attribute__((ext_vector_type(8))) short short8;
typedef __attribute__((ext_vector_type(4))) float f32x4;
typedef __attribute__((ext_vector_type(4))) int i32x4;

static __device__ __forceinline__ unsigned cvtpk(float lo, float hi) {
  __hip_bfloat162 h = __float22bfloat162_rn(make_float2(lo, hi));
  union { __hip_bfloat162 h; unsigned u; } v; v.h = h;
  return v.u;
}
static __device__ __forceinline__ short8 pack8(float4 f0, float4 f1) {
  union { i32x4 i; short8 s; } v;
  v.i.x = cvtpk(f0.x, f0.y);
  v.i.y = cvtpk(f0.z, f0.w);
  v.i.z = cvtpk(f1.x, f1.y);
  v.i.w = cvtpk(f1.z, f1.w);
  return v.s;
}
static __device__ __forceinline__ unsigned short f2bf(float f) {
  union { float f; unsigned u; } v; v.f = f;
  unsigned r = v.u + 0x7FFFu + ((v.u >> 16) & 1u);
  return (unsigned short)(r >> 16);
}
static __device__ __forceinline__ float bf2f(unsigned short u) {
  union { unsigned u; float f; } v; v.u = ((unsigned)u) << 16;
  return v.f;
}

// ---------------------------------------------------------------------------
// agemm (MFMA): aT[b][e][l] = sum_d W_nb[e,d]*atom[b,l,d] + b_nb[e]  (bf16)
//   + s2[b][l] from sAT;  blocks 0..15: v1 columns; block0: c0.
// 256 blocks x 512 thr (8 waves). Block tile 256e x 64l.
// Wave w: e in [w*32, w*32+32), all 64 l. Atom tile staged bf16 in LDS once
// (XOR swizzle); W_nb loaded f32 exactly once per block, cvt_pk to bf16.
// XCD swizzle: all blocks of batch b land on XCD b&7.
// ---------------------------------------------------------------------------
__global__ __launch_bounds__(512) void agemm_kernel(
    const float* __restrict__ atom, const float* __restrict__ W_nb,
    const float* __restrict__ b_nb, const float* __restrict__ W_mol,
    const float* __restrict__ b_mol, const float* __restrict__ align_w,
    const float* __restrict__ align_b, unsigned short* __restrict__ aT,
    float* __restrict__ s2, float* __restrict__ v1c) {
  __shared__ char atile[64 * 256 * 2];      // 32 KB bf16, XOR-swizzled
  __shared__ unsigned short sAT[256 * 68];  // 34 KB
  __shared__ float vp[32][16];

  int t = threadIdx.x;
  int w = t >> 6, lane = t & 63;
  int i = blockIdx.x;
  int x = i & 7, k = i >> 3;
  int b = x + 8 * (k >> 4);          // all blocks of b on XCD b&7
  int l0 = (k & 15) * 64;
  int lo16 = lane & 15, g = lane >> 4;

  // ---- stage atom tile -> LDS bf16 (row r, 32 d per thread) ----
  {
    int r = t >> 3, dseg = (t & 7) * 32;
    const float* src = atom + (size_t)(b * LL + l0 + r) * DD + dseg;
    #pragma unroll
    for (int q = 0; q < 4; ++q) {
      float4 f0 = *(const float4*)(src + q * 8);
      float4 f1 = *(const float4*)(src + q * 8 + 4);
      int byte = ((r * 256 + dseg + q * 8) * 2) ^ ((r & 7) << 4);
      *(short8*)(atile + byte) = pack8(f0, f1);
    }
  }

  // ---- side job: v1 columns (blocks 0..15), c0 (block 0) ----
  if (i < 16) {
    int d0 = i * 16;
    int dl = t & 15, eseg = t >> 4;
    float acc = 0.f;
    #pragma unroll
    for (int q = 0; q < 8; ++q) {
      int e = eseg * 8 + q;
      acc += align_w[e] * W_mol[e * DD + d0 + dl];
    }
    vp[eseg][dl] = acc;
    __syncthreads();
    if (t < 16) {
      float s = 0.f;
      #pragma unroll
      for (int q = 0; q < 32; ++q) s += vp[q][t];
      v1c[d0 + t] = s;
    }
    if (i == 0 && w == 1) {
      float s = b_mol[lane] * align_w[lane] +
                b_mol[lane + 64] * align_w[lane + 64] +
                b_mol[lane + 128] * align_w[lane + 128] +
                b_mol[lane + 192] * align_w[lane + 192];
      #pragma unroll
      for (int off = 32; off > 0; off >>= 1) s += __shfl_xor(s, off, 64);
      if (lane == 0) v1c[256] = s + align_b[0];
    }
  }
  __syncthreads();

  // ---- MFMA: wave w -> e rows [w*32, w*32+32), 64 l from LDS ----
  f32x4 acc[2][4];
  #pragma unroll
  for (int m = 0; m < 2; ++m)
    #pragma unroll
    for (int n = 0; n < 4; ++n) acc[m][n] = f32x4{0.f, 0.f, 0.f, 0.f};

  const float* Ap = W_nb + (size_t)(w * 32 + lo16) * DD + g * 8;

  #pragma unroll 2
  for (int kk = 0; kk < 8; ++kk) {
    short8 af[2];
    #pragma unroll
    for (int m = 0; m < 2; ++m) {
      float4 f0 = *(const float4*)(Ap + m * 16 * DD + kk * 32);
      float4 f1 = *(const float4*)(Ap + m * 16 * DD + kk * 32 + 4);
      af[m] = pack8(f0, f1);
    }
    short8 bf[4];
    #pragma unroll
    for (int n = 0; n < 4; ++n) {
      int l = n * 16 + lo16;
      int byte = ((l * 256 + kk * 32 + g * 8) * 2) ^ ((l & 7) << 4);
      bf[n] = *(const short8*)(atile + byte);
    }
    #pragma unroll
    for (int m = 0; m < 2; ++m)
      #pragma unroll
      for (int n = 0; n < 4; ++n)
        acc[m][n] = __builtin_amdgcn_mfma_f32_16x16x32_bf16(af[m], bf[n],
                                                            acc[m][n], 0, 0, 0);
  }

  // ---- epilogue: +bias, ->bf16 into sAT [256 e][68 l-stride] ----
  #pragma unroll
  for (int m = 0; m < 2; ++m) {
    int e_lo = w * 32 + m * 16 + g * 4;
    float4 bias = *(const float4*)&b_nb[e_lo];
    #pragma unroll
    for (int n = 0; n < 4; ++n) {
      int l = n * 16 + lo16;
      #pragma unroll
      for (int j = 0; j < 4; ++j) {
        float v = acc[m][n][j] + ((const float*)&bias)[j];
        sAT[(e_lo + j) * 68 + l] = f2bf(v);
      }
    }
  }
  __syncthreads();

  // ---- s2 from sAT ----
  {
    int l = t >> 3, ech = (t & 7) * 32;
    float s = 0.f;
    #pragma unroll 8
    for (int q = 0; q < 32; ++q) {
      int e = ech + q;
      s += align_w[DD + e] * bf2f(sAT[e * 68 + l]);
    }
    s += __shfl_xor(s, 1, 64);
    s += __shfl_xor(s, 2, 64);
    s += __shfl_xor(s, 4, 64);
    if ((t & 7) == 0) s2[b * LL + l0 + l] = s;
  }

  // ---- coalesced store to aT ----
  unsigned short* dst = aT + (size_t)b * DD * LL + l0;
  #pragma unroll
  for (int idx = t; idx < 4096; idx += 512) {
    int e = idx >> 4, ch = idx & 15;
    ushort4 v = *(const ushort4*)&sAT[e * 68 + ch * 4];
    *(ushort4*)(dst + (size_t)e * LL + ch * 4) = v;
  }
}

// ---------------------------------------------------------------------------
// attn: block = (b, 16 n-rows), 512 thr = 8 waves. Same XCD swizzle (b&7).
// ---------------------------------------------------------------------------
__global__ __launch_bounds__(512) void attn_kernel(
    const unsigned short* __restrict__ aT, const float* __restrict__ mol,
    const float* __restrict__ v1c, const float* __restrict__ s2,
    const float* __restrict__ amask, const float* __restrict__ smask,
    const float* __restrict__ gamma, const float* __restrict__ beta,
    float* __restrict__ out) {
  __shared__ unsigned short sattn[16 * 1024];  // 32 KB, XOR-swizzled
  __shared__ float ctxp[2][16][DD];            // 32 KB
  __shared__ float v1s[256];
  __shared__ float s1s[16];
  __shared__ float mu_s[16], rs_s[16];
  int i = blockIdx.x;
  int x = i & 7, k = i >> 3;
  int b = x + 8 * (k >> 4);
  int n0 = (k & 15) * 16;
  int t = threadIdx.x, w = t >> 6, lane = t & 63;

  float c0 = v1c[256];
  if (t < 256) v1s[t] = v1c[t];
  __syncthreads();

  // ---- s1: 32 thr/row ----
  {
    int r = t >> 5, off = (t & 31) * 8;
    const float* mr = mol + (size_t)(b * NN + n0 + r) * DD + off;
    float s = 0.f;
    #pragma unroll
    for (int q = 0; q < 2; ++q) {
      float4 f = *(const float4*)(mr + q * 4);
      s += f.x * v1s[off + q * 4] + f.y * v1s[off + q * 4 + 1] +
           f.z * v1s[off + q * 4 + 2] + f.w * v1s[off + q * 4 + 3];
    }
    s += __shfl_xor(s, 1, 64);
    s += __shfl_xor(s, 2, 64);
    s += __shfl_xor(s, 4, 64);
    s += __shfl_xor(s, 8, 64);
    s += __shfl_xor(s, 16, 64);
    if ((t & 31) == 0) s1s[r] = s + c0;
  }
  __syncthreads();

  // ---- softmax: wave w -> rows 2w, 2w+1 ----
  {
    float s2v[16], amv[16], smv[16];
    #pragma unroll
    for (int q = 0; q < 16; ++q) {
      int l = lane + 64 * q;
      s2v[q] = s2[b * LL + l];
      amv[q] = amask[b * LL + l];
      smv[q] = smask[b * LL + l];
    }
    #pragma unroll
    for (int rr = 0; rr < 2; ++rr) {
      int r = w * 2 + rr;
      float s1v = s1s[r];
      float p[16];
      float mx = -INFINITY;
      #pragma unroll
      for (int q = 0; q < 16; ++q) {
        float sc = s1v + s2v[q];
        sc = sc > 0.f ? sc : NEG_SLOPE * sc;
        sc += smv[q];
        p[q] = sc;
        mx = fmaxf(mx, sc);
      }
      #pragma unroll
      for (int off = 32; off > 0; off >>= 1) mx = fmaxf(mx, __shfl_xor(mx, off, 64));
      float sum = 0.f;
      #pragma unroll
      for (int q = 0; q < 16; ++q) {
        p[q] = __expf(p[q] - mx);
        sum += p[q];
      }
      #pragma unroll
      for (int off = 32; off > 0; off >>= 1) sum += __shfl_xor(sum, off, 64);
      float inv = 1.f / sum;
      #pragma unroll
      for (int q = 0; q < 16; ++q) {
        unsigned short bv = f2bf(p[q] * amv[q] * inv);
        int l = lane + 64 * q;
        int byte = ((r * 1024 + l) * 2) ^ ((r & 7) << 4);
        *(unsigned short*)((char*)sattn + byte) = bv;
      }
    }
  }
  __syncthreads();

  // ---- MFMA: wave = e-quadrant (w&3) x l-half (w>>2) ----
  int lo16 = lane & 15, g = lane >> 4;
  int e0 = (w & 3) * 64, lh = w >> 2;
  f32x4 acc[4];
  #pragma unroll
  for (int n = 0; n < 4; ++n) acc[n] = f32x4{0.f, 0.f, 0.f, 0.f};
  const unsigned short* Bp =
      aT + (size_t)b * DD * LL + (size_t)(e0 + lo16) * LL + lh * 512 + g * 8;
  #pragma unroll 4
  for (int kk = 0; kk < 16; ++kk) {
    short8 afr = *(const short8*)((const char*)sattn +
        (((lo16 * 1024 + lh * 512 + kk * 32 + g * 8) * 2) ^ ((lo16 & 7) << 4)));
    #pragma unroll
    for (int n = 0; n < 4; ++n) {
      short8 bfr = *(const short8*)(Bp + (size_t)n * 16 * LL + kk * 32);
      acc[n] = __builtin_amdgcn_mfma_f32_16x16x32_bf16(afr, bfr, acc[n], 0, 0, 0);
    }
  }
  #pragma unroll
  for (int n = 0; n < 4; ++n)
    #pragma unroll
    for (int j = 0; j < 4; ++j)
      ctxp[lh][g * 4 + j][e0 + n * 16 + lo16] = acc[n][j];
  __syncthreads();

  // ---- LN stats: wave w -> rows 2w, 2w+1 ----
  #pragma unroll
  for (int rr = 0; rr < 2; ++rr) {
    int r = w * 2 + rr;
    float s = 0.f, sq = 0.f;
    #pragma unroll
    for (int jj = 0; jj < 4; ++jj) {
      int cc = lane + 64 * jj;
      float v = ctxp[0][r][cc] + ctxp[1][r][cc];
      s += v;
      sq += v * v;
    }
    #pragma unroll
    for (int off = 32; off > 0; off >>= 1) {
      s += __shfl_xor(s, off, 64);
      sq += __shfl_xor(sq, off, 64);
    }
    if (lane == 0) {
      float mu = s * (1.f / 256.f);
      float var = sq * (1.f / 256.f) - mu * mu;
      mu_s[r] = mu;
      rs_s[r] = rsqrtf(var + LN_EPS);
    }
  }
  __syncthreads();

  // ---- store ----
  #pragma unroll
  for (int q = 0; q < 8; ++q) {
    int idx = t + 512 * q;
    int r = idx >> 8, d = idx & 255;
    float v = ctxp[0][r][d] + ctxp[1][r][d];
    out[(size_t)(b * NN + n0 + r) * DD + d] =
        (v - mu_s[r]) * rs_s[r] * gamma[d] + beta[d];
  }
}

// ---------------------------------------------------------------------------
extern "C" void kernel_launch(void* const* d_in, const int* in_sizes, int n_in,
                              void* d_out, int out_size, void* d_ws, size_t ws_size,
                              hipStream_t stream) {
  const float* mol     = (const float*)d_in[0];
  const float* atom    = (const float*)d_in[1];
  const float* amask   = (const float*)d_in[2];
  const float* smask   = (const float*)d_in[3];
  const float* W_mol   = (const float*)d_in[4];
  const float* b_mol   = (const float*)d_in[5];
  const float* W_nb    = (const float*)d_in[6];
  const float* b_nb    = (const float*)d_in[7];
  const float* align_w = (const float*)d_in[8];
  const float* align_b = (const float*)d_in[9];
  const float* gamma   = (const float*)d_in[10];
  const float* beta    = (const float*)d_in[11];
  float* outp = (float*)d_out;

  char* wsb = (char*)d_ws;
  unsigned short* aT = (unsigned short*)wsb;          // 8 MB
  float* s2  = (float*)(wsb + 8388608);               // 64 KB
  float* v1c = s2 + BB * LL;                          // 257 floats

  agemm_kernel<<<256, 512, 0, stream>>>(atom, W_nb, b_nb, W_mol, b_mol,
                                        align_w, align_b, aT, s2, v1c);
  attn_kernel<<<256, 512, 0, stream>>>(aT, mol, v1c, s2, amask, smask,
                                       gamma, beta, outp);
}